// Round 6
// baseline (204.422 us; speedup 1.0000x reference)
//
#include <hip/hip_runtime.h>
#include <hip/hip_bf16.h>

constexpr int B = 2, L = 1024, D = 256, K = 64;
constexpr int N = B * L;          // 2048 rows
constexpr int NC = L / 64;        // 16 chunks of 64 tokens
constexpr int TM_CSTRIDE = 2 * K * D;         // 32768 floats per (b,c)
constexpr int TM_BSTRIDE = NC * TM_CSTRIDE;   // 524288 floats per b

// ---------------------------------------------------------------------------
// K1: fused encoders (k & q) + V projection. 4 rows/block, 512 blocks,
// 512 threads (split-D: half 0 sums d=0..127, half 1 sums d=128..255).
__global__ __launch_bounds__(512, 4) void encv_kernel(
    const float* __restrict__ x,
    const float* __restrict__ pos_k, const float* __restrict__ w1_k,
    const float* __restrict__ b1_k, const float* __restrict__ w2_k,
    const float* __restrict__ b2_k, const float* __restrict__ wa_k,
    const float* __restrict__ ba_k,
    const float* __restrict__ pos_q, const float* __restrict__ w1_q,
    const float* __restrict__ b1_q, const float* __restrict__ w2_q,
    const float* __restrict__ b2_q, const float* __restrict__ wa_q,
    const float* __restrict__ ba_q,
    const float* __restrict__ wv, const float* __restrict__ bv,
    float* __restrict__ kr, float* __restrict__ ki,
    float* __restrict__ qr, float* __restrict__ qi,
    float* __restrict__ V) {
  __shared__ float xs[4][D], xak[4][D], xaq[4][D];     // 12 KB
  __shared__ float hk[4][D], hq[4][D];                 // 8 KB
  __shared__ float part[3][4][D];                      // 12 KB (half-1 partials)
  __shared__ float part2[4][4][K];                     // 4 KB
  __shared__ float phk[4][K], amk[4][K], phq[4][K], amq[4][K];  // 4 KB
  const int tid = threadIdx.x;
  const int row0 = blockIdx.x * 4;
  const int l0 = row0 & (L - 1);
  const int col = tid & 255;
  const int half = tid >> 8;

  // stage x, x+pos_k, x+pos_q (float2 x 512 threads covers 4 rows x 256)
  {
    const int r = tid >> 7, d2 = (tid & 127) * 2;
    const int row = row0 + r, l = l0 + r;
    const float2 xv = *(const float2*)&x[row * D + d2];
    const float2 pk = *(const float2*)&pos_k[l * D + d2];
    const float2 pq = *(const float2*)&pos_q[l * D + d2];
    *(float2*)&xs[r][d2] = xv;
    float2 t1; t1.x = xv.x + pk.x; t1.y = xv.y + pk.y;
    *(float2*)&xak[r][d2] = t1;
    float2 t2; t2.x = xv.x + pq.x; t2.y = xv.y + pq.y;
    *(float2*)&xaq[r][d2] = t2;
  }
  __syncthreads();

  // three D-wide GEMVs (h_k, h_q, V), each half sums 128 of 256 d's
  {
    float ak[4] = {0.f, 0.f, 0.f, 0.f};
    float aq[4] = {0.f, 0.f, 0.f, 0.f};
    float av[4] = {0.f, 0.f, 0.f, 0.f};
    const int dbase = half << 7;
    for (int d4 = dbase; d4 < dbase + 128; d4 += 4) {
      float wk[4], wq[4], wvv[4];
#pragma unroll
      for (int j = 0; j < 4; ++j) {
        wk[j] = w1_k[(d4 + j) * D + col];
        wq[j] = w1_q[(d4 + j) * D + col];
        wvv[j] = wv[(d4 + j) * D + col];
      }
#pragma unroll
      for (int r = 0; r < 4; ++r) {
        const float4 a1 = *(const float4*)&xak[r][d4];
        const float4 a2 = *(const float4*)&xaq[r][d4];
        const float4 a3 = *(const float4*)&xs[r][d4];
        ak[r] += a1.x * wk[0] + a1.y * wk[1] + a1.z * wk[2] + a1.w * wk[3];
        aq[r] += a2.x * wq[0] + a2.y * wq[1] + a2.z * wq[2] + a2.w * wq[3];
        av[r] += a3.x * wvv[0] + a3.y * wvv[1] + a3.z * wvv[2] + a3.w * wvv[3];
      }
    }
    if (half == 1) {
#pragma unroll
      for (int r = 0; r < 4; ++r) {
        part[0][r][col] = ak[r];
        part[1][r][col] = aq[r];
        part[2][r][col] = av[r];
      }
    }
    __syncthreads();
    if (half == 0) {
      const float bk = b1_k[col], bq = b1_q[col], bvv = bv[col];
#pragma unroll
      for (int r = 0; r < 4; ++r) {
        float v = ak[r] + part[0][r][col] + bk;
        hk[r][col] = 0.5f * v * (1.0f + erff(v * 0.70710678f));
        v = aq[r] + part[1][r][col] + bq;
        hq[r][col] = 0.5f * v * (1.0f + erff(v * 0.70710678f));
        V[(row0 + r) * D + col] = av[r] + part[2][r][col] + bvv;
      }
    }
  }
  __syncthreads();

  // second layer: 8 groups of 64 lanes: (type 0..3) x (d-half 0..1)
  {
    const int g = tid >> 6, j = tid & 63;
    const int ty = g & 3, h = g >> 2;
    const float* Wm = (ty == 0) ? w2_k : (ty == 1) ? wa_k : (ty == 2) ? w2_q : wa_q;
    const float (*Am)[D] = (ty == 0) ? hk : (ty == 1) ? xak : (ty == 2) ? hq : xaq;
    float acc[4] = {0.f, 0.f, 0.f, 0.f};
    const int dbase = h << 7;
    for (int d4 = dbase; d4 < dbase + 128; d4 += 4) {
      float wj[4];
#pragma unroll
      for (int jj = 0; jj < 4; ++jj) wj[jj] = Wm[(d4 + jj) * K + j];
#pragma unroll
      for (int r = 0; r < 4; ++r) {
        const float4 a = *(const float4*)&Am[r][d4];
        acc[r] += a.x * wj[0] + a.y * wj[1] + a.z * wj[2] + a.w * wj[3];
      }
    }
    if (h == 1) {
#pragma unroll
      for (int r = 0; r < 4; ++r) part2[ty][r][j] = acc[r];
    }
    __syncthreads();
    if (h == 0) {
      const float* bm = (ty == 0) ? b2_k : (ty == 1) ? ba_k : (ty == 2) ? b2_q : ba_q;
      const float bb = bm[j];
      if (ty == 0 || ty == 2) {
        float (*ph)[K] = (ty == 0) ? phk : phq;
#pragma unroll
        for (int r = 0; r < 4; ++r)
          ph[r][j] = tanhf(acc[r] + part2[ty][r][j] + bb) * 3.14159265358979f;
      } else {
        float (*am)[K] = (ty == 1) ? amk : amq;
#pragma unroll
        for (int r = 0; r < 4; ++r) {
          const float v = acc[r] + part2[ty][r][j] + bb;
          am[r][j] = fmaxf(v, 0.0f) + log1pf(expf(-fabsf(v))) + 0.1f;
        }
      }
    }
  }
  __syncthreads();

  // phasor writes: 512 threads = (enc 0/1) x (4 rows) x (64 j)
  {
    const int kq = tid >> 8, r = (tid >> 6) & 3, j = tid & 63;
    const int row = row0 + r;
    if (kq == 0) {
      const float a = amk[r][j], p = phk[r][j];
      kr[row * K + j] = a * cosf(p);
      ki[row * K + j] = a * sinf(p);
    } else {
      const float a = amq[r][j], p = phq[r][j];
      qr[row * K + j] = a * cosf(p);
      qi[row * K + j] = a * sinf(p);
    }
  }
}

// ---------------------------------------------------------------------------
// K2: per-chunk outer-product sums T[b][c][comp][k][d]. Grid (b,c,dc16)=512.
__global__ __launch_bounds__(256) void tbuild_kernel(
    const float* __restrict__ kr, const float* __restrict__ ki,
    const float* __restrict__ V, float* __restrict__ TM) {
  const int id = blockIdx.x;
  const int dc = id & 15, c = (id >> 4) & 15, b = id >> 8;
  const int tid = threadIdx.x;
  const int n0 = b * L + c * 64;
  const int d = dc * 16 + (tid & 15);
  const int kb = tid >> 4;  // 0..15, owns k = kb*4 .. kb*4+3

  __shared__ float krL[64][68], kiL[64][68];
  for (int e = tid; e < 1024; e += 256) {
    const int t = e >> 4, k4 = (e & 15) * 4;
    *(float4*)&krL[t][k4] = *(const float4*)&kr[(n0 + t) * K + k4];
    *(float4*)&kiL[t][k4] = *(const float4*)&ki[(n0 + t) * K + k4];
  }
  __syncthreads();

  float vcol[64];
#pragma unroll 8
  for (int t = 0; t < 64; ++t) vcol[t] = V[(n0 + t) * D + d];

  float ar[4] = {0.f, 0.f, 0.f, 0.f}, ai[4] = {0.f, 0.f, 0.f, 0.f};
#pragma unroll 4
  for (int t = 0; t < 64; ++t) {
    const float vt = vcol[t];
    const float4 k4r = *(const float4*)&krL[t][kb * 4];
    const float4 k4i = *(const float4*)&kiL[t][kb * 4];
    ar[0] += k4r.x * vt; ar[1] += k4r.y * vt; ar[2] += k4r.z * vt; ar[3] += k4r.w * vt;
    ai[0] += k4i.x * vt; ai[1] += k4i.y * vt; ai[2] += k4i.z * vt; ai[3] += k4i.w * vt;
  }

  const size_t base = (size_t)b * TM_BSTRIDE + (size_t)c * TM_CSTRIDE;
#pragma unroll
  for (int i = 0; i < 4; ++i) {
    const int k = kb * 4 + i;
    TM[base + (size_t)k * D + d] = ar[i];
    TM[base + (size_t)(K + k) * D + d] = ai[i];
  }
}

// ---------------------------------------------------------------------------
// K3: in-place exclusive prefix over c.
__global__ __launch_bounds__(256) void scan_kernel(float* __restrict__ TM) {
  const int col = blockIdx.x * 256 + threadIdx.x;
  const int d = col & 255;
  const int k = (col >> 8) & 63;
  const int comp = (col >> 14) & 1;
  const int b = col >> 15;
  size_t idx = (size_t)b * TM_BSTRIDE + (size_t)comp * (K * D) + (size_t)k * D + d;
  float run = 0.f;
#pragma unroll
  for (int c = 0; c < NC; ++c, idx += TM_CSTRIDE) {
    const float t = TM[idx];
    TM[idx] = run;
    run += t;
  }
}

// ---------------------------------------------------------------------------
// K4: fused retrieval + norm + LN + output projection + residual.
// 2 rows/block, 1024 blocks, 512 threads (split-D / split-k halves).
__global__ __launch_bounds__(512, 4) void out_kernel(
    const float* __restrict__ qr, const float* __restrict__ qi,
    const float* __restrict__ kr, const float* __restrict__ ki,
    const float* __restrict__ V, const float* __restrict__ TM,
    const float* __restrict__ x,
    const float* __restrict__ ln_g, const float* __restrict__ ln_b,
    const float* __restrict__ wo, const float* __restrict__ bo,
    float* __restrict__ out) {
  const int tid = threadIdx.x;
  const int col = tid & 255;
  const int half = tid >> 8;
  const int r0 = blockIdx.x * 2;
  const int b = r0 >> 10;
  const int l0 = r0 & (L - 1);
  const int c = l0 >> 6;
  const int lo = l0 & 63;                  // even, 0..62
  const int n0 = b * L + c * 64;
  const int nrows = lo + 2;                // K-rows needed (t <= lo+1)

  __shared__ float qrL[2][K], qiL[2][K];
  __shared__ float krL[64][68], kiL[64][68];
  __shared__ float SL[2][64];
  __shared__ float partM[2][D];
  __shared__ float rn[2][D];
  __shared__ float red[2][2][4];

  if (tid < 128) {
    const int r = tid >> 6, k = tid & 63;
    qrL[r][k] = qr[(r0 + r) * K + k];
    qiL[r][k] = qi[(r0 + r) * K + k];
  }
  for (int e = tid; e < nrows * 16; e += 512) {
    const int t = e >> 4, k4 = (e & 15) * 4;
    *(float4*)&krL[t][k4] = *(const float4*)&kr[(n0 + t) * K + k4];
    *(float4*)&kiL[t][k4] = *(const float4*)&ki[(n0 + t) * K + k4];
  }
  __syncthreads();

  // intra-chunk scores
  if (tid < 128) {
    const int rq = tid >> 6, t = tid & 63;
    float s = 0.f;
    if (t <= lo + rq) {
#pragma unroll
      for (int k4 = 0; k4 < K; k4 += 4) {
        const float4 a = *(const float4*)&qrL[rq][k4];
        const float4 bb = *(const float4*)&qiL[rq][k4];
        const float4 kk = *(const float4*)&krL[t][k4];
        const float4 kki = *(const float4*)&kiL[t][k4];
        s += a.x * kk.x + a.y * kk.y + a.z * kk.z + a.w * kk.w +
             bb.x * kki.x + bb.y * kki.y + bb.z * kki.z + bb.w * kki.w;
      }
    }
    SL[rq][t] = s;
  }
  __syncthreads();

  // M-term (split k-halves) + intra-chunk S.V (split t-parity)
  float a0 = 0.f, a1 = 0.f;
  {
    const float* Mr = TM + (size_t)b * TM_BSTRIDE + (size_t)c * TM_CSTRIDE;
    const float* Mi = Mr + K * D;
    const int kbase = half << 5;
    for (int k4 = kbase; k4 < kbase + 32; k4 += 4) {
      const float4 q0r = *(const float4*)&qrL[0][k4];
      const float4 q0i = *(const float4*)&qiL[0][k4];
      const float4 q1r = *(const float4*)&qrL[1][k4];
      const float4 q1i = *(const float4*)&qiL[1][k4];
#pragma unroll
      for (int j = 0; j < 4; ++j) {
        const float mr = Mr[(size_t)(k4 + j) * D + col];
        const float mi = Mi[(size_t)(k4 + j) * D + col];
        a0 += ((const float*)&q0r)[j] * mr + ((const float*)&q0i)[j] * mi;
        a1 += ((const float*)&q1r)[j] * mr + ((const float*)&q1i)[j] * mi;
      }
    }
    const int tmax = lo + 1;
    for (int t = half; t <= tmax; t += 2) {
      const float vt = V[(n0 + t) * D + col];
      a0 += SL[0][t] * vt;
      a1 += SL[1][t] * vt;
    }
  }
  if (half == 1) { partM[0][col] = a0; partM[1][col] = a1; }
  __syncthreads();

  float val0 = 0.f, val1 = 0.f;
  if (half == 0) {
    val0 = (a0 + partM[0][col]) * rsqrtf((float)(l0 + 1) * 64.0f);
    val1 = (a1 + partM[1][col]) * rsqrtf((float)(l0 + 2) * 64.0f);
    const int w = tid >> 6;
    float v = val0, v2 = val0 * val0;
    for (int off = 32; off > 0; off >>= 1) {
      v += __shfl_xor(v, off, 64);
      v2 += __shfl_xor(v2, off, 64);
    }
    if ((tid & 63) == 0) { red[0][0][w] = v; red[0][1][w] = v2; }
    v = val1; v2 = val1 * val1;
    for (int off = 32; off > 0; off >>= 1) {
      v += __shfl_xor(v, off, 64);
      v2 += __shfl_xor(v2, off, 64);
    }
    if ((tid & 63) == 0) { red[1][0][w] = v; red[1][1][w] = v2; }
  }
  __syncthreads();

  if (half == 0) {
    const float g = ln_g[col], bb = ln_b[col];
    {
      const float s = red[0][0][0] + red[0][0][1] + red[0][0][2] + red[0][0][3];
      const float sq = red[0][1][0] + red[0][1][1] + red[0][1][2] + red[0][1][3];
      const float mu = s * (1.0f / 256.0f);
      const float var = sq * (1.0f / 256.0f) - mu * mu;
      rn[0][col] = (val0 - mu) * rsqrtf(var + 1e-5f) * g + bb;
    }
    {
      const float s = red[1][0][0] + red[1][0][1] + red[1][0][2] + red[1][0][3];
      const float sq = red[1][1][0] + red[1][1][1] + red[1][1][2] + red[1][1][3];
      const float mu = s * (1.0f / 256.0f);
      const float var = sq * (1.0f / 256.0f) - mu * mu;
      rn[1][col] = (val1 - mu) * rsqrtf(var + 1e-5f) * g + bb;
    }
  }
  __syncthreads();

  // out = x + rn @ wo + bo   (split d-halves)
  float ao0 = 0.f, ao1 = 0.f;
  {
    const int dbase = half << 7;
    for (int d4 = dbase; d4 < dbase + 128; d4 += 4) {
      float wj[4];
#pragma unroll
      for (int j = 0; j < 4; ++j) wj[j] = wo[(d4 + j) * D + col];
      const float4 r0v = *(const float4*)&rn[0][d4];
      const float4 r1v = *(const float4*)&rn[1][d4];
      ao0 += r0v.x * wj[0] + r0v.y * wj[1] + r0v.z * wj[2] + r0v.w * wj[3];
      ao1 += r1v.x * wj[0] + r1v.y * wj[1] + r1v.z * wj[2] + r1v.w * wj[3];
    }
  }
  if (half == 1) { partM[0][col] = ao0; partM[1][col] = ao1; }
  __syncthreads();
  if (half == 0) {
    const float bo_ = bo[col];
    out[(r0 + 0) * D + col] = x[(r0 + 0) * D + col] + ao0 + partM[0][col] + bo_;
    out[(r0 + 1) * D + col] = x[(r0 + 1) * D + col] + ao1 + partM[1][col] + bo_;
  }
}

// ---------------------------------------------------------------------------
extern "C" void kernel_launch(void* const* d_in, const int* in_sizes, int n_in,
                              void* d_out, int out_size, void* d_ws, size_t ws_size,
                              hipStream_t stream) {
  (void)in_sizes; (void)n_in; (void)out_size; (void)ws_size;
  const float* x    = (const float*)d_in[0];
  const float* pos_k= (const float*)d_in[1];
  const float* w1_k = (const float*)d_in[2];
  const float* b1_k = (const float*)d_in[3];
  const float* w2_k = (const float*)d_in[4];
  const float* b2_k = (const float*)d_in[5];
  const float* wa_k = (const float*)d_in[6];
  const float* ba_k = (const float*)d_in[7];
  const float* pos_q= (const float*)d_in[8];
  const float* w1_q = (const float*)d_in[9];
  const float* b1_q = (const float*)d_in[10];
  const float* w2_q = (const float*)d_in[11];
  const float* b2_q = (const float*)d_in[12];
  const float* wa_q = (const float*)d_in[13];
  const float* ba_q = (const float*)d_in[14];
  const float* wv   = (const float*)d_in[15];
  const float* bv   = (const float*)d_in[16];
  const float* ln_g = (const float*)d_in[17];
  const float* ln_b = (const float*)d_in[18];
  const float* wo   = (const float*)d_in[19];
  const float* bo   = (const float*)d_in[20];

  float* ws = (float*)d_ws;
  float* kr = ws;                          // N*K
  float* ki = kr + (size_t)N * K;
  float* qr = ki + (size_t)N * K;
  float* qi = qr + (size_t)N * K;
  float* V  = qi + (size_t)N * K;          // N*D
  float* TM = V + (size_t)N * D;           // B*NC*2*K*D floats (4 MB)

  encv_kernel<<<N / 4, 512, 0, stream>>>(
      x, pos_k, w1_k, b1_k, w2_k, b2_k, wa_k, ba_k,
      pos_q, w1_q, b1_q, w2_q, b2_q, wa_q, ba_q, wv, bv,
      kr, ki, qr, qi, V);
  tbuild_kernel<<<B * NC * 16, 256, 0, stream>>>(kr, ki, V, TM);
  scan_kernel<<<(B * 2 * K * D) / 256, 256, 0, stream>>>(TM);
  out_kernel<<<N / 2, 512, 0, stream>>>(qr, qi, kr, ki, V, TM, x,
                                        ln_g, ln_b, wo, bo, (float*)d_out);
}

// Round 7
// 165.213 us; speedup vs baseline: 1.2373x; 1.2373x over previous
//
#include <hip/hip_runtime.h>
#include <hip/hip_bf16.h>

typedef __attribute__((ext_vector_type(8))) short short8;
typedef __attribute__((ext_vector_type(4))) float float4v;

constexpr int B = 2, L = 1024, D = 256, K = 64;
constexpr int N = B * L;          // 2048 rows
constexpr int NC = L / 64;        // 16 chunks of 64 tokens
constexpr int TM_CSTRIDE = 2 * K * D;
constexpr int TM_BSTRIDE = NC * TM_CSTRIDE;

// WT arena (ushort units):
// layer1 mats g in {w1_k, w1_q, wv}: hi at g*131072, lo at +65536
// layer2 mats m in {w2_k, wa_k, w2_q, wa_q}: hi at WT2_OFF + m*32768, lo +16384
constexpr int WT2_OFF = 393216;

__device__ __forceinline__ ushort bf16_hi(float v) {
  return (ushort)(__float_as_uint(v) >> 16);
}
__device__ __forceinline__ float hi_f(float v) {
  return __uint_as_float(__float_as_uint(v) & 0xFFFF0000u);
}
__device__ __forceinline__ ushort bf16_rne(float v) {
  uint b = __float_as_uint(v);
  b += 0x7FFF + ((b >> 16) & 1);
  return (ushort)(b >> 16);
}

// ---------------------------------------------------------------------------
// K0: transpose + hi/lo split all encoder weights into WT arena.
// 64 blocks: 48 for the three 256x256 mats (16 64x64 tiles each),
// 16 for the four 256x64 mats (4 64-row tiles each).
__global__ __launch_bounds__(256) void prep_kernel(
    const float* __restrict__ w1_k, const float* __restrict__ w1_q,
    const float* __restrict__ wv,
    const float* __restrict__ w2_k, const float* __restrict__ wa_k,
    const float* __restrict__ w2_q, const float* __restrict__ wa_q,
    ushort* __restrict__ WT) {
  __shared__ float Lt[64][65];
  const int bi = blockIdx.x, tid = threadIdx.x;
  const float* src;
  int ncols, k0, n0;
  ushort* dhi;
  int losz;
  if (bi < 48) {
    const int m = bi >> 4, t = bi & 15;
    src = (m == 0) ? w1_k : (m == 1) ? w1_q : wv;
    ncols = 256; k0 = (t >> 2) * 64; n0 = (t & 3) * 64;
    dhi = WT + m * 131072; losz = 65536;
  } else {
    const int m = (bi - 48) >> 2, kt = (bi - 48) & 3;
    src = (m == 0) ? w2_k : (m == 1) ? wa_k : (m == 2) ? w2_q : wa_q;
    ncols = 64; k0 = kt * 64; n0 = 0;
    dhi = WT + WT2_OFF + m * 32768; losz = 16384;
  }
  ushort* dlo = dhi + losz;
  for (int p = 0; p < 16; ++p) {
    const int kr = p * 4 + (tid >> 6), nc = tid & 63;
    Lt[kr][nc] = src[(k0 + kr) * ncols + n0 + nc];
  }
  __syncthreads();
  const int n = tid >> 2, kq = tid & 3;
  uint uh[8], ul[8];
  for (int i = 0; i < 8; ++i) {
    const float v0 = Lt[kq * 16 + 2 * i][n];
    const float v1 = Lt[kq * 16 + 2 * i + 1][n];
    uh[i] = (uint)bf16_hi(v0) | ((uint)bf16_hi(v1) << 16);
    ul[i] = (uint)bf16_rne(v0 - hi_f(v0)) | ((uint)bf16_rne(v1 - hi_f(v1)) << 16);
  }
  const int oidx = (n0 + n) * 256 + k0 + kq * 16;
  *(uint4*)&dhi[oidx] = make_uint4(uh[0], uh[1], uh[2], uh[3]);
  *(uint4*)&dhi[oidx + 8] = make_uint4(uh[4], uh[5], uh[6], uh[7]);
  *(uint4*)&dlo[oidx] = make_uint4(ul[0], ul[1], ul[2], ul[3]);
  *(uint4*)&dlo[oidx + 8] = make_uint4(ul[4], ul[5], ul[6], ul[7]);
}

// ---------------------------------------------------------------------------
// K1: layer-1 as 3 GEMMs [2048,256]@[256,256] via MFMA bf16x3.
// grid: g(3) x row-tile32(64) x col-half128(2) = 384 blocks, 256 threads.
__global__ __launch_bounds__(256) void enc1_kernel(
    const float* __restrict__ x, const float* __restrict__ pos_k,
    const float* __restrict__ pos_q,
    const float* __restrict__ b1_k, const float* __restrict__ b1_q,
    const float* __restrict__ bv, const ushort* __restrict__ WT,
    float* __restrict__ hk, float* __restrict__ hq, float* __restrict__ V) {
  __shared__ __align__(16) ushort Ah[32][40], Al[32][40];
  __shared__ __align__(16) ushort Bh[128][40], Bl[128][40];
  const int tid = threadIdx.x;
  const int g = blockIdx.x / 128;
  const int rem = blockIdx.x % 128;
  const int row0 = (rem >> 1) * 32, nb = (rem & 1) * 128;
  const float* pos = (g == 0) ? pos_k : (g == 1) ? pos_q : nullptr;
  const ushort* Wh = WT + g * 131072;
  const ushort* Wl = Wh + 65536;
  const int w = tid >> 6, lane = tid & 63;
  const int m16 = lane & 15, quad = lane >> 4;

  float4v acc[2][2] = {};

  for (int k0 = 0; k0 < 256; k0 += 32) {
    __syncthreads();
    {  // stage A (32 rows x 32 k), built on the fly, hi/lo split
      const int r = tid >> 3, kc = (tid & 7) * 4;
      const int row = row0 + r, l = row & (L - 1);
      float4 xv = *(const float4*)&x[row * D + k0 + kc];
      if (pos) {
        const float4 pv = *(const float4*)&pos[l * D + k0 + kc];
        xv.x += pv.x; xv.y += pv.y; xv.z += pv.z; xv.w += pv.w;
      }
      ushort4 h4, l4;
      h4.x = bf16_hi(xv.x); l4.x = bf16_rne(xv.x - hi_f(xv.x));
      h4.y = bf16_hi(xv.y); l4.y = bf16_rne(xv.y - hi_f(xv.y));
      h4.z = bf16_hi(xv.z); l4.z = bf16_rne(xv.z - hi_f(xv.z));
      h4.w = bf16_hi(xv.w); l4.w = bf16_rne(xv.w - hi_f(xv.w));
      *(ushort4*)&Ah[r][kc] = h4;
      *(ushort4*)&Al[r][kc] = l4;
    }
#pragma unroll
    for (int p = 0; p < 2; ++p) {  // stage B (128 n x 32 k) from WT planes
      const int n = (tid >> 2) + p * 64, chunk = tid & 3;
      const int ga = (nb + n) * 256 + k0 + chunk * 8;
      *(uint4*)&Bh[n][chunk * 8] = *(const uint4*)&Wh[ga];
      *(uint4*)&Bl[n][chunk * 8] = *(const uint4*)&Wl[ga];
    }
    __syncthreads();

    short8 afh[2], afl[2], bfh[2], bfl[2];
#pragma unroll
    for (int r = 0; r < 2; ++r) {
      afh[r] = *(const short8*)&Ah[r * 16 + m16][quad * 8];
      afl[r] = *(const short8*)&Al[r * 16 + m16][quad * 8];
    }
#pragma unroll
    for (int c = 0; c < 2; ++c) {
      const int col = w * 32 + c * 16 + m16;
      bfh[c] = *(const short8*)&Bh[col][quad * 8];
      bfl[c] = *(const short8*)&Bl[col][quad * 8];
    }
#pragma unroll
    for (int r = 0; r < 2; ++r)
#pragma unroll
      for (int c = 0; c < 2; ++c) {
        acc[r][c] = __builtin_amdgcn_mfma_f32_16x16x32_bf16(afh[r], bfh[c], acc[r][c], 0, 0, 0);
        acc[r][c] = __builtin_amdgcn_mfma_f32_16x16x32_bf16(afh[r], bfl[c], acc[r][c], 0, 0, 0);
        acc[r][c] = __builtin_amdgcn_mfma_f32_16x16x32_bf16(afl[r], bfh[c], acc[r][c], 0, 0, 0);
      }
  }

  float* outp = (g == 0) ? hk : (g == 1) ? hq : V;
  const float* bp = (g == 0) ? b1_k : (g == 1) ? b1_q : bv;
#pragma unroll
  for (int c = 0; c < 2; ++c) {
    const int colg = nb + w * 32 + c * 16 + m16;
    const float bias = bp[colg];
#pragma unroll
    for (int r = 0; r < 2; ++r)
#pragma unroll
      for (int j = 0; j < 4; ++j) {
        const int rowg = row0 + r * 16 + quad * 4 + j;
        float v = acc[r][c][j] + bias;
        if (g < 2) v = 0.5f * v * (1.0f + erff(v * 0.70710678f));
        outp[rowg * D + colg] = v;
      }
  }
}

// ---------------------------------------------------------------------------
// K2: layer-2 (phase & amp GEMMs [2048,256]@[256,64]) + phasor epilogue.
// grid: enc(2) x row-tile16(128) = 256 blocks, 256 threads.
__global__ __launch_bounds__(256) void enc2_kernel(
    const float* __restrict__ x, const float* __restrict__ pos_k,
    const float* __restrict__ pos_q, const float* __restrict__ hk,
    const float* __restrict__ hq,
    const float* __restrict__ b2_k, const float* __restrict__ ba_k,
    const float* __restrict__ b2_q, const float* __restrict__ ba_q,
    const ushort* __restrict__ WT,
    float* __restrict__ kr, float* __restrict__ ki,
    float* __restrict__ qr, float* __restrict__ qi) {
  __shared__ __align__(16) ushort Ahh[16][40], Ahl[16][40], Axh[16][40], Axl[16][40];
  __shared__ __align__(16) ushort B2h[64][40], B2l[64][40], Bah[64][40], Bal[64][40];
  const int tid = threadIdx.x;
  const int e = blockIdx.x >> 7;
  const int r0g = (blockIdx.x & 127) * 16;
  const float* hsrc = e ? hq : hk;
  const float* pos = e ? pos_q : pos_k;
  const ushort* W2h = WT + WT2_OFF + (e ? 2 : 0) * 32768;
  const ushort* W2l = W2h + 16384;
  const ushort* Wah = WT + WT2_OFF + (e ? 3 : 1) * 32768;
  const ushort* Wal = Wah + 16384;
  const int w = tid >> 6, lane = tid & 63;
  const int m16 = lane & 15, quad = lane >> 4;

  float4v accP = {}, accA = {};
  for (int k0 = 0; k0 < 256; k0 += 32) {
    __syncthreads();
    {  // stage A: h (from global) and xa = x+pos (on the fly), hi/lo
      const int r = tid >> 4, kc = (tid & 15) * 2;
      const int row = r0g + r, l = row & (L - 1);
      const float2 hv = *(const float2*)&hsrc[row * D + k0 + kc];
      const float2 xv = *(const float2*)&x[row * D + k0 + kc];
      const float2 pv = *(const float2*)&pos[l * D + k0 + kc];
      const float a0 = xv.x + pv.x, a1 = xv.y + pv.y;
      ushort2 t;
      t.x = bf16_hi(hv.x); t.y = bf16_hi(hv.y); *(ushort2*)&Ahh[r][kc] = t;
      t.x = bf16_rne(hv.x - hi_f(hv.x)); t.y = bf16_rne(hv.y - hi_f(hv.y));
      *(ushort2*)&Ahl[r][kc] = t;
      t.x = bf16_hi(a0); t.y = bf16_hi(a1); *(ushort2*)&Axh[r][kc] = t;
      t.x = bf16_rne(a0 - hi_f(a0)); t.y = bf16_rne(a1 - hi_f(a1));
      *(ushort2*)&Axl[r][kc] = t;
    }
    {  // stage B: w2 and wa hi/lo (64 n x 32 k each)
      const int n = tid >> 2, chunk = tid & 3;
      const int ga = n * 256 + k0 + chunk * 8;
      *(uint4*)&B2h[n][chunk * 8] = *(const uint4*)&W2h[ga];
      *(uint4*)&B2l[n][chunk * 8] = *(const uint4*)&W2l[ga];
      *(uint4*)&Bah[n][chunk * 8] = *(const uint4*)&Wah[ga];
      *(uint4*)&Bal[n][chunk * 8] = *(const uint4*)&Wal[ga];
    }
    __syncthreads();

    const short8 ahh = *(const short8*)&Ahh[m16][quad * 8];
    const short8 ahl = *(const short8*)&Ahl[m16][quad * 8];
    const short8 axh = *(const short8*)&Axh[m16][quad * 8];
    const short8 axl = *(const short8*)&Axl[m16][quad * 8];
    const int col = w * 16 + m16;
    const short8 b2h = *(const short8*)&B2h[col][quad * 8];
    const short8 b2l = *(const short8*)&B2l[col][quad * 8];
    const short8 bah = *(const short8*)&Bah[col][quad * 8];
    const short8 bal = *(const short8*)&Bal[col][quad * 8];
    accP = __builtin_amdgcn_mfma_f32_16x16x32_bf16(ahh, b2h, accP, 0, 0, 0);
    accP = __builtin_amdgcn_mfma_f32_16x16x32_bf16(ahh, b2l, accP, 0, 0, 0);
    accP = __builtin_amdgcn_mfma_f32_16x16x32_bf16(ahl, b2h, accP, 0, 0, 0);
    accA = __builtin_amdgcn_mfma_f32_16x16x32_bf16(axh, bah, accA, 0, 0, 0);
    accA = __builtin_amdgcn_mfma_f32_16x16x32_bf16(axh, bal, accA, 0, 0, 0);
    accA = __builtin_amdgcn_mfma_f32_16x16x32_bf16(axl, bah, accA, 0, 0, 0);
  }

  float* pr = e ? qr : kr;
  float* pim = e ? qi : ki;
  const float* b2 = e ? b2_q : b2_k;
  const float* ba = e ? ba_q : ba_k;
  const int colk = w * 16 + m16;
  const float b2v = b2[colk], bav = ba[colk];
#pragma unroll
  for (int j = 0; j < 4; ++j) {
    const int row = r0g + quad * 4 + j;
    const float ph = tanhf(accP[j] + b2v) * 3.14159265358979f;
    const float av = accA[j] + bav;
    const float am = fmaxf(av, 0.0f) + log1pf(expf(-fabsf(av))) + 0.1f;
    pr[row * K + colk] = am * cosf(ph);
    pim[row * K + colk] = am * sinf(ph);
  }
}

// ---------------------------------------------------------------------------
// K3: per-chunk outer-product sums T[b][c][comp][k][d]. Grid (b,c,dc16)=512.
__global__ __launch_bounds__(256) void tbuild_kernel(
    const float* __restrict__ kr, const float* __restrict__ ki,
    const float* __restrict__ V, float* __restrict__ TM) {
  const int id = blockIdx.x;
  const int dc = id & 15, c = (id >> 4) & 15, b = id >> 8;
  const int tid = threadIdx.x;
  const int n0 = b * L + c * 64;
  const int d = dc * 16 + (tid & 15);
  const int kb = tid >> 4;

  __shared__ float krL[64][68], kiL[64][68];
  for (int e = tid; e < 1024; e += 256) {
    const int t = e >> 4, k4 = (e & 15) * 4;
    *(float4*)&krL[t][k4] = *(const float4*)&kr[(n0 + t) * K + k4];
    *(float4*)&kiL[t][k4] = *(const float4*)&ki[(n0 + t) * K + k4];
  }
  __syncthreads();

  float vcol[64];
#pragma unroll 8
  for (int t = 0; t < 64; ++t) vcol[t] = V[(n0 + t) * D + d];

  float ar[4] = {0.f, 0.f, 0.f, 0.f}, ai[4] = {0.f, 0.f, 0.f, 0.f};
#pragma unroll 4
  for (int t = 0; t < 64; ++t) {
    const float vt = vcol[t];
    const float4 k4r = *(const float4*)&krL[t][kb * 4];
    const float4 k4i = *(const float4*)&kiL[t][kb * 4];
    ar[0] += k4r.x * vt; ar[1] += k4r.y * vt; ar[2] += k4r.z * vt; ar[3] += k4r.w * vt;
    ai[0] += k4i.x * vt; ai[1] += k4i.y * vt; ai[2] += k4i.z * vt; ai[3] += k4i.w * vt;
  }

  const size_t base = (size_t)b * TM_BSTRIDE + (size_t)c * TM_CSTRIDE;
#pragma unroll
  for (int i = 0; i < 4; ++i) {
    const int k = kb * 4 + i;
    TM[base + (size_t)k * D + d] = ar[i];
    TM[base + (size_t)(K + k) * D + d] = ai[i];
  }
}

// ---------------------------------------------------------------------------
// K4: in-place exclusive prefix over c.
__global__ __launch_bounds__(256) void scan_kernel(float* __restrict__ TM) {
  const int col = blockIdx.x * 256 + threadIdx.x;
  const int d = col & 255;
  const int k = (col >> 8) & 63;
  const int comp = (col >> 14) & 1;
  const int b = col >> 15;
  size_t idx = (size_t)b * TM_BSTRIDE + (size_t)comp * (K * D) + (size_t)k * D + d;
  float run = 0.f;
#pragma unroll
  for (int c = 0; c < NC; ++c, idx += TM_CSTRIDE) {
    const float t = TM[idx];
    TM[idx] = run;
    run += t;
  }
}

// ---------------------------------------------------------------------------
// K5: fused retrieval + norm + LN + output projection + residual.
// 2 rows/block, 1024 blocks, 256 threads (round-5 version).
__global__ __launch_bounds__(256) void out_kernel(
    const float* __restrict__ qr, const float* __restrict__ qi,
    const float* __restrict__ kr, const float* __restrict__ ki,
    const float* __restrict__ V, const float* __restrict__ TM,
    const float* __restrict__ x,
    const float* __restrict__ ln_g, const float* __restrict__ ln_b,
    const float* __restrict__ wo, const float* __restrict__ bo,
    float* __restrict__ out) {
  const int tid = threadIdx.x;
  const int r0 = blockIdx.x * 2;
  const int b = r0 >> 10;
  const int l0 = r0 & (L - 1);
  const int c = l0 >> 6;
  const int lo = l0 & 63;
  const int n0 = b * L + c * 64;
  const int nrows = lo + 2;

  __shared__ float qrL[2][K], qiL[2][K];
  __shared__ float krL[64][68], kiL[64][68];
  __shared__ float SL[2][64];
  __shared__ float rn[2][D];
  __shared__ float red[2][2][4];

  if (tid < 128) {
    const int r = tid >> 6, k = tid & 63;
    qrL[r][k] = qr[(r0 + r) * K + k];
    qiL[r][k] = qi[(r0 + r) * K + k];
  }
  for (int e = tid; e < nrows * 16; e += 256) {
    const int t = e >> 4, k4 = (e & 15) * 4;
    *(float4*)&krL[t][k4] = *(const float4*)&kr[(n0 + t) * K + k4];
    *(float4*)&kiL[t][k4] = *(const float4*)&ki[(n0 + t) * K + k4];
  }
  __syncthreads();

  if (tid < 128) {
    const int rq = tid >> 6, t = tid & 63;
    float s = 0.f;
    if (t <= lo + rq) {
#pragma unroll
      for (int k4 = 0; k4 < K; k4 += 4) {
        const float4 a = *(const float4*)&qrL[rq][k4];
        const float4 bb = *(const float4*)&qiL[rq][k4];
        const float4 kk = *(const float4*)&krL[t][k4];
        const float4 kki = *(const float4*)&kiL[t][k4];
        s += a.x * kk.x + a.y * kk.y + a.z * kk.z + a.w * kk.w +
             bb.x * kki.x + bb.y * kki.y + bb.z * kki.z + bb.w * kki.w;
      }
    }
    SL[rq][t] = s;
  }
  __syncthreads();

  float acc0 = 0.f, acc1 = 0.f;
  const float* Mr = TM + (size_t)b * TM_BSTRIDE + (size_t)c * TM_CSTRIDE;
  const float* Mi = Mr + K * D;
  for (int k4 = 0; k4 < K; k4 += 4) {
    const float4 q0r = *(const float4*)&qrL[0][k4];
    const float4 q0i = *(const float4*)&qiL[0][k4];
    const float4 q1r = *(const float4*)&qrL[1][k4];
    const float4 q1i = *(const float4*)&qiL[1][k4];
#pragma unroll
    for (int j = 0; j < 4; ++j) {
      const float mr = Mr[(size_t)(k4 + j) * D + tid];
      const float mi = Mi[(size_t)(k4 + j) * D + tid];
      acc0 += ((const float*)&q0r)[j] * mr + ((const float*)&q0i)[j] * mi;
      acc1 += ((const float*)&q1r)[j] * mr + ((const float*)&q1i)[j] * mi;
    }
  }
  {
    const int tmax = lo + 1;
    for (int t = 0; t <= tmax; ++t) {
      const float vt = V[(n0 + t) * D + tid];
      acc0 += SL[0][t] * vt;
      acc1 += SL[1][t] * vt;
    }
  }

  float val[2];
  val[0] = acc0 * rsqrtf((float)(l0 + 1) * 64.0f);
  val[1] = acc1 * rsqrtf((float)(l0 + 2) * 64.0f);
  const int w = tid >> 6;
#pragma unroll
  for (int rq = 0; rq < 2; ++rq) {
    float v = val[rq], v2 = v * v;
    for (int off = 32; off > 0; off >>= 1) {
      v += __shfl_xor(v, off, 64);
      v2 += __shfl_xor(v2, off, 64);
    }
    if ((tid & 63) == 0) { red[rq][0][w] = v; red[rq][1][w] = v2; }
  }
  __syncthreads();

  const float g = ln_g[tid], bb = ln_b[tid];
#pragma unroll
  for (int rq = 0; rq < 2; ++rq) {
    const float s = red[rq][0][0] + red[rq][0][1] + red[rq][0][2] + red[rq][0][3];
    const float sq = red[rq][1][0] + red[rq][1][1] + red[rq][1][2] + red[rq][1][3];
    const float mu = s * (1.0f / 256.0f);
    const float var = sq * (1.0f / 256.0f) - mu * mu;
    rn[rq][tid] = (val[rq] - mu) * rsqrtf(var + 1e-5f) * g + bb;
  }
  __syncthreads();

  float ao0, ao1;
  ao0 = ao1 = bo[tid];
  for (int d4 = 0; d4 < D; d4 += 4) {
    float wj[4];
#pragma unroll
    for (int j = 0; j < 4; ++j) wj[j] = wo[(d4 + j) * D + tid];
    const float4 r0v = *(const float4*)&rn[0][d4];
    const float4 r1v = *(const float4*)&rn[1][d4];
    ao0 += r0v.x * wj[0] + r0v.y * wj[1] + r0v.z * wj[2] + r0v.w * wj[3];
    ao1 += r1v.x * wj[0] + r1v.y * wj[1] + r1v.z * wj[2] + r1v.w * wj[3];
  }
  out[(r0 + 0) * D + tid] = x[(r0 + 0) * D + tid] + ao0;
  out[(r0 + 1) * D + tid] = x[(r0 + 1) * D + tid] + ao1;
}

// ---------------------------------------------------------------------------
extern "C" void kernel_launch(void* const* d_in, const int* in_sizes, int n_in,
                              void* d_out, int out_size, void* d_ws, size_t ws_size,
                              hipStream_t stream) {
  (void)in_sizes; (void)n_in; (void)out_size; (void)ws_size;
  const float* x    = (const float*)d_in[0];
  const float* pos_k= (const float*)d_in[1];
  const float* w1_k = (const float*)d_in[2];
  const float* b1_k = (const float*)d_in[3];
  const float* w2_k = (const float*)d_in[4];
  const float* b2_k = (const float*)d_in[5];
  const float* wa_k = (const float*)d_in[6];
  const float* ba_k = (const float*)d_in[7];
  const float* pos_q= (const float*)d_in[8];
  const float* w1_q = (const float*)d_in[9];
  const float* b1_q = (const float*)d_in[10];
  const float* w2_q = (const float*)d_in[11];
  const float* b2_q = (const float*)d_in[12];
  const float* wa_q = (const float*)d_in[13];
  const float* ba_q = (const float*)d_in[14];
  const float* wv   = (const float*)d_in[15];
  const float* bv   = (const float*)d_in[16];
  const float* ln_g = (const float*)d_in[17];
  const float* ln_b = (const float*)d_in[18];
  const float* wo   = (const float*)d_in[19];
  const float* bo   = (const float*)d_in[20];

  float* ws = (float*)d_ws;
  float* kr = ws;                          // N*K
  float* ki = kr + (size_t)N * K;
  float* qr = ki + (size_t)N * K;
  float* qi = qr + (size_t)N * K;
  float* V  = qi + (size_t)N * K;          // N*D
  float* TM = V + (size_t)N * D;           // B*NC*2*K*D (4 MB)
  float* hk = TM + (size_t)B * NC * 2 * K * D;  // N*D
  float* hq = hk + (size_t)N * D;          // N*D
  ushort* WT = (ushort*)(hq + (size_t)N * D);   // 524288 ushorts (1 MB)

  prep_kernel<<<64, 256, 0, stream>>>(w1_k, w1_q, wv, w2_k, wa_k, w2_q, wa_q, WT);
  enc1_kernel<<<384, 256, 0, stream>>>(x, pos_k, pos_q, b1_k, b1_q, bv, WT, hk, hq, V);
  enc2_kernel<<<256, 256, 0, stream>>>(x, pos_k, pos_q, hk, hq,
                                       b2_k, ba_k, b2_q, ba_q, WT, kr, ki, qr, qi);
  tbuild_kernel<<<B * NC * 16, 256, 0, stream>>>(kr, ki, V, TM);
  scan_kernel<<<(B * 2 * K * D) / 256, 256, 0, stream>>>(TM);
  out_kernel<<<N / 2, 256, 0, stream>>>(qr, qi, kr, ki, V, TM, x,
                                        ln_g, ln_b, wo, bo, (float*)d_out);
}